// Round 1
// baseline (118.029 us; speedup 1.0000x reference)
//
#include <hip/hip_runtime.h>

// Damped EMA: h[t] = a*x[t] + (1-a)*h[t-1], h[-1]=0, over (B,T,D) fp32.
// Chunked along T with truncated warm-up window (r^W below tolerance).
// Round 6: warm-up W 8->4. r^4 = 1e-4, so truncated-history error is
// ~1e-4 * |h| (~5e-4 worst case) vs pass threshold ~9.7e-2 and the
// existing fp32-FFT-reference error floor of ~1.6e-2 -> negligible.
// Cuts read overfetch 25% -> 12.5% (traffic 151 -> 142.6 MB).
// Structure otherwise identical to Round 5 (CHUNK=32, double-buffered
// groups of 8, nontemporal stores).

#define B_ 4
#define T_ 4096
#define D_ 1024
#define CHUNK 32    // timesteps per block
#define DB 256      // floats of D per block = 64 lanes * float4
#define WFIX 4      // unrolled warm-up window (r^4 = 1e-4 for r=0.1)
#define GRP 8       // timesteps per pipelined group
#define NGRP (CHUNK / GRP)

typedef float v4f __attribute__((ext_vector_type(4)));

__global__ __launch_bounds__(64)
void ema_scan_kernel(const float* __restrict__ x,
                     const float* __restrict__ alpha,
                     float* __restrict__ out) {
    const int lane    = threadIdx.x;            // 0..63
    const int dSplits = D_ / DB;                // 4
    const int chunk   = blockIdx.x / dSplits;   // 0..T_/CHUNK-1
    const int dseg    = blockIdx.x % dSplits;
    const int b       = blockIdx.y;
    const int d0      = dseg * DB + lane * 4;
    const int t0      = chunk * CHUNK;

    const float a = alpha[0];
    const float r = 1.0f - a;

    // Window length so truncated history contributes < ~1e-4 relative.
    // (e^-9 = 1.2e-4; for r=0.1 this gives W = ceil(9/2.303) = 4 = WFIX.)
    int W;
    if (!(r > 0.0f)) {
        W = 0;                       // alpha >= 1: no history matters
    } else if (r >= 1.0f) {
        W = t0;                      // alpha <= 0: need full history (exact)
    } else {
        W = (int)ceilf(9.0f / (-logf(r)));
        if (W < WFIX) W = WFIX;      // round up to the unrolled fast path
        if (W > t0)   W = t0;        // chunk 0: W=0, exact
    }

    const float* xp = x   + ((size_t)b * T_ + (size_t)(t0 - W)) * D_ + d0;
    float*       op = out + ((size_t)b * T_ + (size_t)t0) * D_ + d0;

    v4f h = (v4f)(0.0f);

    if (W == WFIX) {
        // Fast path: warm-up + group0 loads all issued before any wait.
        v4f w[WFIX];
        v4f g[2][GRP];
        const float* xm = xp + (size_t)WFIX * D_;   // start of main region
#pragma unroll
        for (int i = 0; i < WFIX; ++i) w[i] = *(const v4f*)(xp + (size_t)i * D_);
#pragma unroll
        for (int j = 0; j < GRP; ++j)  g[0][j] = *(const v4f*)(xm + (size_t)j * D_);

#pragma unroll
        for (int i = 0; i < WFIX; ++i) h = r * h + a * w[i];

#pragma unroll
        for (int gi = 0; gi < NGRP; ++gi) {
            if (gi + 1 < NGRP) {
                const float* xn = xm + (size_t)(gi + 1) * GRP * D_;
#pragma unroll
                for (int j = 0; j < GRP; ++j)
                    g[(gi + 1) & 1][j] = *(const v4f*)(xn + (size_t)j * D_);
            }
#pragma unroll
            for (int j = 0; j < GRP; ++j) {
                h = r * h + a * g[gi & 1][j];
                __builtin_nontemporal_store(
                    h, (v4f*)(op + ((size_t)gi * GRP + j) * D_));
            }
        }
    } else {
        // Generic path (chunk 0 or unusual alpha): simple serial scan.
        for (int i = 0; i < W; ++i) {
            v4f t = *(const v4f*)xp;
            xp += D_;
            h = r * h + a * t;
        }
        for (int j = 0; j < CHUNK; ++j) {
            v4f t = *(const v4f*)xp;
            xp += D_;
            h = r * h + a * t;
            __builtin_nontemporal_store(h, (v4f*)(op + (size_t)j * D_));
        }
    }
}

extern "C" void kernel_launch(void* const* d_in, const int* in_sizes, int n_in,
                              void* d_out, int out_size, void* d_ws, size_t ws_size,
                              hipStream_t stream) {
    const float* x     = (const float*)d_in[0];
    const float* alpha = (const float*)d_in[1];
    float*       out   = (float*)d_out;

    dim3 grid((T_ / CHUNK) * (D_ / DB), B_);  // 512 x 4 = 2048 blocks
    ema_scan_kernel<<<grid, 64, 0, stream>>>(x, alpha, out);
}

// Round 2
// 109.687 us; speedup vs baseline: 1.0760x; 1.0760x over previous
//
#include <hip/hip_runtime.h>

// Damped EMA: h[t] = a*x[t] + (1-a)*h[t-1], h[-1]=0, over (B,T,D) fp32.
// Chunked along T with truncated warm-up window (r^W below tolerance).
// Round 7: CHUNK 32->16 (at fixed W=4). Doubles grid to 4096 blocks ->
// 16 waves/CU (was 8), attacking the ~3us latency-hiding gap (kernel ran
// at 5.6 TB/s vs 6.3 achievable; only-8-waves/CU was the suspect).
// Traffic cost: warm-up overfetch 12.5% -> 25% of reads (+4.2 MB, +0.7us
// floor) -- worth it if the occupancy theory is right.
// W=4 kept: r^4 = 1e-4 truncation << 9.7e-2 pass threshold and << 1.6e-2
// fp32-FFT reference error floor.

#define B_ 4
#define T_ 4096
#define D_ 1024
#define CHUNK 16    // timesteps per block
#define DB 256      // floats of D per block = 64 lanes * float4
#define WFIX 4      // unrolled warm-up window (r^4 = 1e-4 for r=0.1)
#define GRP 8       // timesteps per pipelined group
#define NGRP (CHUNK / GRP)

typedef float v4f __attribute__((ext_vector_type(4)));

__global__ __launch_bounds__(64)
void ema_scan_kernel(const float* __restrict__ x,
                     const float* __restrict__ alpha,
                     float* __restrict__ out) {
    const int lane    = threadIdx.x;            // 0..63
    const int dSplits = D_ / DB;                // 4
    const int chunk   = blockIdx.x / dSplits;   // 0..T_/CHUNK-1
    const int dseg    = blockIdx.x % dSplits;
    const int b       = blockIdx.y;
    const int d0      = dseg * DB + lane * 4;
    const int t0      = chunk * CHUNK;

    const float a = alpha[0];
    const float r = 1.0f - a;

    // Window length so truncated history contributes < ~1e-4 relative.
    // (e^-9 = 1.2e-4; for r=0.1 this gives W = ceil(9/2.303) = 4 = WFIX.)
    int W;
    if (!(r > 0.0f)) {
        W = 0;                       // alpha >= 1: no history matters
    } else if (r >= 1.0f) {
        W = t0;                      // alpha <= 0: need full history (exact)
    } else {
        W = (int)ceilf(9.0f / (-logf(r)));
        if (W < WFIX) W = WFIX;      // round up to the unrolled fast path
        if (W > t0)   W = t0;        // chunk 0: W=0, exact
    }

    const float* xp = x   + ((size_t)b * T_ + (size_t)(t0 - W)) * D_ + d0;
    float*       op = out + ((size_t)b * T_ + (size_t)t0) * D_ + d0;

    v4f h = (v4f)(0.0f);

    if (W == WFIX) {
        // Fast path: warm-up + group0 loads all issued before any wait.
        v4f w[WFIX];
        v4f g[2][GRP];
        const float* xm = xp + (size_t)WFIX * D_;   // start of main region
#pragma unroll
        for (int i = 0; i < WFIX; ++i) w[i] = *(const v4f*)(xp + (size_t)i * D_);
#pragma unroll
        for (int j = 0; j < GRP; ++j)  g[0][j] = *(const v4f*)(xm + (size_t)j * D_);

#pragma unroll
        for (int i = 0; i < WFIX; ++i) h = r * h + a * w[i];

#pragma unroll
        for (int gi = 0; gi < NGRP; ++gi) {
            if (gi + 1 < NGRP) {
                const float* xn = xm + (size_t)(gi + 1) * GRP * D_;
#pragma unroll
                for (int j = 0; j < GRP; ++j)
                    g[(gi + 1) & 1][j] = *(const v4f*)(xn + (size_t)j * D_);
            }
#pragma unroll
            for (int j = 0; j < GRP; ++j) {
                h = r * h + a * g[gi & 1][j];
                __builtin_nontemporal_store(
                    h, (v4f*)(op + ((size_t)gi * GRP + j) * D_));
            }
        }
    } else {
        // Generic path (chunk 0 or unusual alpha): simple serial scan.
        for (int i = 0; i < W; ++i) {
            v4f t = *(const v4f*)xp;
            xp += D_;
            h = r * h + a * t;
        }
        for (int j = 0; j < CHUNK; ++j) {
            v4f t = *(const v4f*)xp;
            xp += D_;
            h = r * h + a * t;
            __builtin_nontemporal_store(h, (v4f*)(op + (size_t)j * D_));
        }
    }
}

extern "C" void kernel_launch(void* const* d_in, const int* in_sizes, int n_in,
                              void* d_out, int out_size, void* d_ws, size_t ws_size,
                              hipStream_t stream) {
    const float* x     = (const float*)d_in[0];
    const float* alpha = (const float*)d_in[1];
    float*       out   = (float*)d_out;

    dim3 grid((T_ / CHUNK) * (D_ / DB), B_);  // 1024 x 4 = 4096 blocks
    ema_scan_kernel<<<grid, 64, 0, stream>>>(x, alpha, out);
}